// Round 2
// baseline (182.784 us; speedup 1.0000x reference)
//
#include <hip/hip_runtime.h>

// ---------------- problem constants ----------------
#define BATCH   65536
#define NPAGES  4096
#define KD      128

// ws layout (bytes). Total 18,309,120 B (~17.5 MB).
#define OFF_Q    0u          // Q bf16 [65536][128]                 16 MB
#define OFF_K    16777216u   // K bf16, 64-page chunks, XOR-swizzled 1 MB
#define OFF_V    17825792u   // V^T bf16 [48][4096] (aug: ones col 40) 384 KB
#define OFF_W1T  18219008u   // W1^T bf16 [256][48] (k padded 36->48) 24 KB
#define OFF_W2T  18243584u   // W2^T bf16 [128][256]                 64 KB
#define WS_NEEDED 18309120u

typedef short          bfr8   __attribute__((ext_vector_type(8)));
typedef unsigned short u16x8  __attribute__((ext_vector_type(8)));
typedef unsigned short u16x4  __attribute__((ext_vector_type(4)));
typedef float          f32x2v __attribute__((ext_vector_type(2)));
typedef float          f32x4v __attribute__((ext_vector_type(4)));
typedef float          f32x16v __attribute__((ext_vector_type(16)));

__device__ __forceinline__ unsigned short f2bf(float x){
  unsigned int u = __builtin_bit_cast(unsigned int, x);
  unsigned int r = (u + 0x7fffu + ((u >> 16) & 1u)) >> 16;   // RNE
  return (unsigned short)r;
}
__device__ __forceinline__ float sigmoidf_(float x){ return 1.0f / (1.0f + __expf(-x)); }

__device__ __forceinline__ f32x16v mfma32(bfr8 a, bfr8 b, f32x16v c){
  return __builtin_amdgcn_mfma_f32_32x32x16_bf16(a, b, c, 0, 0, 0);
}
__device__ __forceinline__ f32x4v mfma16(bfr8 a, bfr8 b, f32x4v c){
  return __builtin_amdgcn_mfma_f32_16x16x32_bf16(a, b, c, 0, 0, 0);
}
__device__ __forceinline__ f32x16v zero16(){
  f32x16v v;
  #pragma unroll
  for (int i = 0; i < 16; ++i) v[i] = 0.f;
  return v;
}
__device__ __forceinline__ f32x4v zero4(){
  f32x4v v;
  #pragma unroll
  for (int i = 0; i < 4; ++i) v[i] = 0.f;
  return v;
}

// ---------------- prep: bf16 conversions / layouts ----------------
// 307200 threads total, exact segments.
__global__ void prep_kernel(const float* __restrict__ mappings, const float* __restrict__ keys,
                            const float* __restrict__ perms, const float* __restrict__ W1,
                            const float* __restrict__ W2, char* __restrict__ ws){
  int t = blockIdx.x * 256 + threadIdx.x;
  if (t < 65536){                       // K: 4096 pages x 16 granules of 8 cols
    int p = t >> 4, c8 = t & 15;
    const float* src = keys + (size_t)p * 128 + c8 * 8;
    u16x8 val;
    #pragma unroll
    for (int j = 0; j < 8; ++j) val[j] = f2bf(src[j]);
    int r = p & 63, chunk = p >> 6;
    int byteoff = (r * 256 + c8 * 16) ^ ((r & 7) << 4);   // pre-swizzle (involution)
    *(u16x8*)(ws + OFF_K + (size_t)chunk * 16384 + byteoff) = val;
  } else if (t < 65536 + 12288){        // W1^T [256][48], k>=36 zero
    int i = t - 65536; int cc = i / 48, k = i - cc * 48;
    float v = (k < 36) ? W1[(size_t)k * 256 + cc] : 0.0f;
    ((unsigned short*)(ws + OFF_W1T))[cc * 48 + k] = f2bf(v);
  } else if (t < 65536 + 12288 + 32768){ // W2^T [128][256]
    int i = t - (65536 + 12288); int cc = i >> 8, k = i & 255;
    ((unsigned short*)(ws + OFF_W2T))[cc * 256 + k] = f2bf(W2[(size_t)k * 128 + cc]);
  } else {                              // V^T [48][4096]: rows 0..35 map[36+j], 36..39 perms, 40 ones, 41..47 zero
    int i = t - (65536 + 12288 + 32768); int j = i >> 12, p = i & 4095;
    float v;
    if (j < 36)      v = mappings[(size_t)p * 72 + 36 + j];
    else if (j < 40) v = perms[(size_t)p * 4 + (j - 36)];
    else if (j == 40) v = 1.0f;
    else             v = 0.0f;
    ((unsigned short*)(ws + OFF_V))[j * 4096 + p] = f2bf(v);
  }
}

// ---------------- MLP: query = gelu(pb@W1+b1)@W2+b2 -> Q bf16 ----------------
// 512 WGs x 256 thr, 128 rows/WG. Swapped-operand MFMA (computes h^T / q^T) so
// C-fragments write 4-consecutive-col b64 chunks. Also copies offset bits to out.
__global__ __launch_bounds__(256, 2) void mlp_kernel(const float* __restrict__ vab,
    const float* __restrict__ b1, const float* __restrict__ b2,
    char* __restrict__ ws, float* __restrict__ out){
  __shared__ __align__(16) unsigned short pb_lds[128 * 64];   // swizzled bf16, 16 KB
  __shared__ __align__(16) unsigned short h_lds[128 * 256];   // swizzled bf16, 64 KB
  const int tid = threadIdx.x;
  const int bb = blockIdx.x * 128;

  for (int i = tid; i < 128 * 64; i += 256){                  // stage page bits (pad k 36..63 = 0)
    int r = i >> 6, k = i & 63;
    float v = (k < 36) ? vab[(size_t)(bb + r) * 48 + 12 + k] : 0.0f;
    int byte = (r * 128 + k * 2) ^ ((r & 7) << 4);
    *(unsigned short*)((char*)pb_lds + byte) = f2bf(v);
  }
  for (int i = tid; i < 128 * 12; i += 256){                  // offset-bit passthrough
    int r = i / 12, c = i - r * 12;
    out[(size_t)(bb + r) * 52 + c] = vab[(size_t)(bb + r) * 48 + c];
  }
  __syncthreads();

  const int lane = tid & 63, wv = tid >> 6;
  const int lo = lane & 31, hi = lane >> 5;
  const unsigned short* w1t = (const unsigned short*)(ws + OFF_W1T);

  // phase 1: h^T = W1^T @ pb^T ; C row = hcol, col = brow -> b64 writes into h[brow][hcol]
  #pragma unroll
  for (int art = 0; art < 2; ++art){
    const int hcol0 = (wv * 2 + art) * 32;
    bfr8 af[3];
    #pragma unroll
    for (int ks = 0; ks < 3; ++ks)
      af[ks] = *(const bfr8*)(w1t + (size_t)(hcol0 + lo) * 48 + 8 * hi + 16 * ks);
    for (int bct = 0; bct < 4; ++bct){
      f32x16v acc = zero16();
      #pragma unroll
      for (int ks = 0; ks < 3; ++ks){
        int row = bct * 32 + lo;
        int byte = row * 128 + ((16 * hi + 32 * ks) ^ ((row & 7) << 4));
        bfr8 bf = *(const bfr8*)((const char*)pb_lds + byte);
        acc = mfma32(af[ks], bf, acc);
      }
      int brow = bct * 32 + lo;
      #pragma unroll
      for (int w = 0; w < 4; ++w){
        u16x4 pk;
        #pragma unroll
        for (int rs = 0; rs < 4; ++rs){
          int hcol = hcol0 + rs + 8 * w + 4 * hi;       // C row = (reg&3)+8*(reg>>2)+4*hi
          float x = acc[4 * w + rs] + b1[hcol];
          float gl = 0.5f * x * (1.0f + erff(x * 0.70710678118654752f));
          pk[rs] = f2bf(gl);
        }
        int byte = (brow * 512 + (hcol0 + 8 * w + 4 * hi) * 2) ^ ((brow & 7) << 4);
        *(u16x4*)((char*)h_lds + byte) = pk;
      }
    }
  }
  __syncthreads();

  // phase 2: q^T = W2^T @ h^T -> Qws[brow][qcol] bf16
  const unsigned short* w2t = (const unsigned short*)(ws + OFF_W2T);
  unsigned short* qws = (unsigned short*)(ws + OFF_Q);
  const int qcol0 = wv * 32;
  bfr8 af2[16];
  #pragma unroll
  for (int ks = 0; ks < 16; ++ks)
    af2[ks] = *(const bfr8*)(w2t + (size_t)(qcol0 + lo) * 256 + 8 * hi + 16 * ks);
  for (int bct = 0; bct < 4; ++bct){
    f32x16v acc = zero16();
    int brow = bct * 32 + lo;
    #pragma unroll
    for (int ks = 0; ks < 16; ++ks){
      int byte = brow * 512 + ((16 * hi + 32 * ks) ^ ((brow & 7) << 4));
      bfr8 bf = *(const bfr8*)((const char*)h_lds + byte);
      acc = mfma32(af2[ks], bf, acc);
    }
    #pragma unroll
    for (int w = 0; w < 4; ++w){
      u16x4 pk;
      #pragma unroll
      for (int rs = 0; rs < 4; ++rs){
        int qcol = qcol0 + rs + 8 * w + 4 * hi;
        pk[rs] = f2bf(acc[4 * w + rs] + b2[qcol]);
      }
      *(u16x4*)(qws + (size_t)(bb + brow) * 128 + qcol0 + 8 * w + 4 * hi) = pk;
    }
  }
}

// ---------------- attention: softmax(QK^T/T) @ Vaug, fused ----------------
// 512 WGs x 256 thr; 128 rows/WG (32/wave); 64 chunks of 64 pages.
// No max-subtraction needed: |logit| is O(1), exp cannot overflow in f32.
__global__ __launch_bounds__(256, 2) void attn_kernel(const char* __restrict__ ws,
    const float* __restrict__ temp_p, float* __restrict__ out){
  __shared__ __align__(16) unsigned short k_lds[64 * 128];    // swizzled, 16 KB
  __shared__ __align__(16) float pt_lds[4][64 * 38];          // per-wave P^T, pitch 38 f32

  const int tid = threadIdx.x;
  const int lane = tid & 63, wv = tid >> 6;
  const int lo = lane & 31, hi = lane >> 5;
  const int g4 = lane >> 4, r16 = lane & 15;
  const int bb = blockIdx.x * 128;

  const unsigned short* qws = (const unsigned short*)(ws + OFF_Q);
  const unsigned short* kws = (const unsigned short*)(ws + OFF_K);
  const unsigned short* vt  = (const unsigned short*)(ws + OFF_V);

  const float invt = 1.0f / fmaxf(fabsf(temp_p[0]), 0.1f);
  const int qrow = bb + wv * 32 + lo;

  bfr8 qf[8];                                        // Q row held in registers
  #pragma unroll
  for (int ks = 0; ks < 8; ++ks)
    qf[ks] = *(const bfr8*)(qws + (size_t)qrow * 128 + 8 * hi + 16 * ks);

  f32x4v acc[2][3];
  #pragma unroll
  for (int rt = 0; rt < 2; ++rt)
    #pragma unroll
    for (int ct = 0; ct < 3; ++ct) acc[rt][ct] = zero4();

  float* myp = pt_lds[wv];

  for (int c = 0; c < 64; ++c){
    __syncthreads();
    {                                                // stage 16 KB K chunk (pre-swizzled, linear copy)
      const u16x8* src = (const u16x8*)(kws + (size_t)c * 8192);
      u16x8* dst = (u16x8*)k_lds;
      #pragma unroll
      for (int i = 0; i < 4; ++i) dst[i * 256 + tid] = src[i * 256 + tid];
    }
    __syncthreads();

    bfr8 vf[3][2];                                   // V-frags straight from L2
    #pragma unroll
    for (int ct = 0; ct < 3; ++ct)
      #pragma unroll
      for (int k2 = 0; k2 < 2; ++k2)
        vf[ct][k2] = *(const bfr8*)(vt + (size_t)(16 * ct + r16) * 4096 + c * 64 + 32 * k2 + 8 * g4);

    // S = Q @ K^T (two 32-page tiles)
    f32x16v s0 = zero16(), s1 = zero16();
    #pragma unroll
    for (int ks = 0; ks < 8; ++ks){
      int cb = ((16 * ks + 8 * hi) * 2) ^ ((lo & 7) << 4);
      bfr8 k0 = *(const bfr8*)((const char*)k_lds + lo * 256 + cb);
      bfr8 k1 = *(const bfr8*)((const char*)k_lds + (32 + lo) * 256 + cb);
      s0 = mfma32(qf[ks], k0, s0);
      s1 = mfma32(qf[ks], k1, s1);
    }

    // P = exp(S*invt) -> per-wave LDS P^T[page][qidx]
    #pragma unroll
    for (int pt = 0; pt < 2; ++pt){
      f32x16v s = pt ? s1 : s0;
      #pragma unroll
      for (int w = 0; w < 4; ++w){
        f32x2v a, b;
        a[0] = __expf(s[4 * w + 0] * invt); a[1] = __expf(s[4 * w + 1] * invt);
        b[0] = __expf(s[4 * w + 2] * invt); b[1] = __expf(s[4 * w + 3] * invt);
        int base = (32 * pt + lo) * 38 + 8 * w + 4 * hi;
        *(f32x2v*)(myp + base)     = a;
        *(f32x2v*)(myp + base + 2) = b;
      }
    }

    // acc += P @ Vaug (16x16x32; ones column gives denominator for free)
    #pragma unroll
    for (int k2 = 0; k2 < 2; ++k2){
      #pragma unroll
      for (int rt = 0; rt < 2; ++rt){
        bfr8 pf;
        #pragma unroll
        for (int j = 0; j < 8; ++j){
          float pv = myp[(32 * k2 + 8 * g4 + j) * 38 + 16 * rt + r16];
          pf[j] = (short)f2bf(pv);
        }
        #pragma unroll
        for (int ct = 0; ct < 3; ++ct)
          acc[rt][ct] = mfma16(pf, vf[ct][k2], acc[rt][ct]);
      }
    }
  }

  // epilogue: denom = V-col 40 (ct=2, lane&15==8); broadcast via wave-private LDS
  float* dn = myp;
  if (r16 == 8){
    #pragma unroll
    for (int rt = 0; rt < 2; ++rt)
      #pragma unroll
      for (int rs = 0; rs < 4; ++rs)
        dn[16 * rt + 4 * g4 + rs] = acc[rt][2][rs];
  }
  #pragma unroll
  for (int rt = 0; rt < 2; ++rt){
    #pragma unroll
    for (int rs = 0; rs < 4; ++rs){
      int rloc = 16 * rt + 4 * g4 + rs;
      float dinv = 1.0f / dn[rloc];
      size_t rowg = (size_t)(bb + wv * 32 + rloc);
      #pragma unroll
      for (int ct = 0; ct < 3; ++ct){
        int vcol = 16 * ct + r16;
        float v = acc[rt][ct][rs] * dinv;
        if (vcol < 36)       out[rowg * 52 + 12 + vcol] = sigmoidf_(v);
        else if (vcol < 40)  out[rowg * 52 + 48 + (vcol - 36)] = sigmoidf_(v);
        // vcol==40 is the denominator column, 41..47 padding: skip
      }
    }
  }
}

extern "C" void kernel_launch(void* const* d_in, const int* in_sizes, int n_in,
                              void* d_out, int out_size, void* d_ws, size_t ws_size,
                              hipStream_t stream){
  const float* vab      = (const float*)d_in[0];
  const float* mappings = (const float*)d_in[1];
  const float* keys     = (const float*)d_in[2];
  const float* perms    = (const float*)d_in[3];
  const float* W1       = (const float*)d_in[4];
  const float* b1       = (const float*)d_in[5];
  const float* W2       = (const float*)d_in[6];
  const float* b2       = (const float*)d_in[7];
  const float* temp     = (const float*)d_in[8];
  float* out = (float*)d_out;
  char*  ws  = (char*)d_ws;
  if (ws_size < WS_NEEDED) return;   // loud failure instead of OOB corruption

  prep_kernel<<<1200, 256, 0, stream>>>(mappings, keys, perms, W1, W2, ws);
  mlp_kernel<<<512, 256, 0, stream>>>(vab, b1, b2, ws, out);
  attn_kernel<<<512, 256, 0, stream>>>(ws, temp, out);
}

// Round 3
// 176.818 us; speedup vs baseline: 1.0337x; 1.0337x over previous
//
#include <hip/hip_runtime.h>

// ---------------- problem constants ----------------
#define BATCH   65536
#define NPAGES  4096
#define KD      128

// ws layout (bytes). Total 18,309,120 B (~17.5 MB).
#define OFF_Q    0u          // Q bf16 [65536][128]                 16 MB
#define OFF_K    16777216u   // K bf16, 64-page chunks, XOR-swizzled 1 MB
#define OFF_V    17825792u   // V^T bf16 [48][4096] (aug: ones col 40) 384 KB
#define OFF_W1T  18219008u   // W1^T bf16 [256][48] (k padded 36->48) 24 KB
#define OFF_W2T  18243584u   // W2^T bf16 [128][256]                 64 KB
#define WS_NEEDED 18309120u

typedef short          bfr8   __attribute__((ext_vector_type(8)));
typedef unsigned short u16x8  __attribute__((ext_vector_type(8)));
typedef unsigned short u16x4  __attribute__((ext_vector_type(4)));
typedef unsigned int   u32x4  __attribute__((ext_vector_type(4)));
typedef float          f32x4v __attribute__((ext_vector_type(4)));
typedef float          f32x16v __attribute__((ext_vector_type(16)));

__device__ __forceinline__ unsigned short f2bf(float x){
  unsigned int u = __builtin_bit_cast(unsigned int, x);
  unsigned int r = (u + 0x7fffu + ((u >> 16) & 1u)) >> 16;   // RNE
  return (unsigned short)r;
}
__device__ __forceinline__ float sigmoidf_(float x){ return 1.0f / (1.0f + __expf(-x)); }

__device__ __forceinline__ f32x16v mfma32(bfr8 a, bfr8 b, f32x16v c){
  return __builtin_amdgcn_mfma_f32_32x32x16_bf16(a, b, c, 0, 0, 0);
}
__device__ __forceinline__ f32x16v zero16(){
  f32x16v v;
  #pragma unroll
  for (int i = 0; i < 16; ++i) v[i] = 0.f;
  return v;
}

// exp + pack one 32-key S-tile into two PV A-fragments (keys 0-15, 16-31).
// Lane (lo,hi) holds S^T[key=crow(r,hi)][query=lo]; after cvt_pk + permlane32_swap
// lane holds P[query=lo][k=8*hi+j] per 16-key tile (exact HK T12 path).
__device__ __forceinline__ void tile_pack(const f32x16v& s, float scl, bfr8& paA, bfr8& paB){
  unsigned w[8];
  #pragma unroll
  for (int p = 0; p < 8; ++p){
    float a = __expf(s[2*p]   * scl);
    float b = __expf(s[2*p+1] * scl);
    asm("v_cvt_pk_bf16_f32 %0, %1, %2" : "=v"(w[p]) : "v"(a), "v"(b));
  }
  // swap vdst[32:63] <-> vsrc[0:31]
  asm("v_permlane32_swap_b32 %0, %1" : "+v"(w[0]), "+v"(w[2]));
  asm("v_permlane32_swap_b32 %0, %1" : "+v"(w[1]), "+v"(w[3]));
  asm("v_permlane32_swap_b32 %0, %1" : "+v"(w[4]), "+v"(w[6]));
  asm("v_permlane32_swap_b32 %0, %1" : "+v"(w[5]), "+v"(w[7]));
  u32x4 t0 = {w[0], w[1], w[2], w[3]};
  u32x4 t1 = {w[4], w[5], w[6], w[7]};
  paA = __builtin_bit_cast(bfr8, t0);
  paB = __builtin_bit_cast(bfr8, t1);
}

// ---------------- prep: bf16 conversions / layouts ----------------
__global__ void prep_kernel(const float* __restrict__ mappings, const float* __restrict__ keys,
                            const float* __restrict__ perms, const float* __restrict__ W1,
                            const float* __restrict__ W2, char* __restrict__ ws){
  int t = blockIdx.x * 256 + threadIdx.x;
  if (t < 65536){                       // K: 4096 pages x 16 granules of 8 cols
    int p = t >> 4, c8 = t & 15;
    const float* src = keys + (size_t)p * 128 + c8 * 8;
    u16x8 val;
    #pragma unroll
    for (int j = 0; j < 8; ++j) val[j] = f2bf(src[j]);
    int r = p & 63, chunk = p >> 6;
    int byteoff = (r * 256 + c8 * 16) ^ ((r & 7) << 4);   // pre-swizzle (involution)
    *(u16x8*)(ws + OFF_K + (size_t)chunk * 16384 + byteoff) = val;
  } else if (t < 65536 + 12288){        // W1^T [256][48], k>=36 zero
    int i = t - 65536; int cc = i / 48, k = i - cc * 48;
    float v = (k < 36) ? W1[(size_t)k * 256 + cc] : 0.0f;
    ((unsigned short*)(ws + OFF_W1T))[cc * 48 + k] = f2bf(v);
  } else if (t < 65536 + 12288 + 32768){ // W2^T [128][256]
    int i = t - (65536 + 12288); int cc = i >> 8, k = i & 255;
    ((unsigned short*)(ws + OFF_W2T))[cc * 256 + k] = f2bf(W2[(size_t)k * 128 + cc]);
  } else {                              // V^T [48][4096]: rows 0..35 map[36+j], 36..39 perms, 40 ones, 41..47 zero
    int i = t - (65536 + 12288 + 32768); int j = i >> 12, p = i & 4095;
    float v;
    if (j < 36)      v = mappings[(size_t)p * 72 + 36 + j];
    else if (j < 40) v = perms[(size_t)p * 4 + (j - 36)];
    else if (j == 40) v = 1.0f;
    else             v = 0.0f;
    ((unsigned short*)(ws + OFF_V))[j * 4096 + p] = f2bf(v);
  }
}

// ---------------- MLP: query = gelu(pb@W1+b1)@W2+b2 -> Q bf16 ----------------
__global__ __launch_bounds__(256, 2) void mlp_kernel(const float* __restrict__ vab,
    const float* __restrict__ b1, const float* __restrict__ b2,
    char* __restrict__ ws, float* __restrict__ out){
  __shared__ __align__(16) unsigned short pb_lds[128 * 64];   // swizzled bf16, 16 KB
  __shared__ __align__(16) unsigned short h_lds[128 * 256];   // swizzled bf16, 64 KB
  const int tid = threadIdx.x;
  const int bb = blockIdx.x * 128;

  for (int i = tid; i < 128 * 64; i += 256){                  // stage page bits (pad k 36..63 = 0)
    int r = i >> 6, k = i & 63;
    float v = (k < 36) ? vab[(size_t)(bb + r) * 48 + 12 + k] : 0.0f;
    int byte = (r * 128 + k * 2) ^ ((r & 7) << 4);
    *(unsigned short*)((char*)pb_lds + byte) = f2bf(v);
  }
  for (int i = tid; i < 128 * 12; i += 256){                  // offset-bit passthrough
    int r = i / 12, c = i - r * 12;
    out[(size_t)(bb + r) * 52 + c] = vab[(size_t)(bb + r) * 48 + c];
  }
  __syncthreads();

  const int lane = tid & 63, wv = tid >> 6;
  const int lo = lane & 31, hi = lane >> 5;
  const unsigned short* w1t = (const unsigned short*)(ws + OFF_W1T);

  // phase 1: h^T = W1^T @ pb^T
  #pragma unroll
  for (int art = 0; art < 2; ++art){
    const int hcol0 = (wv * 2 + art) * 32;
    bfr8 af[3];
    #pragma unroll
    for (int ks = 0; ks < 3; ++ks)
      af[ks] = *(const bfr8*)(w1t + (size_t)(hcol0 + lo) * 48 + 8 * hi + 16 * ks);
    for (int bct = 0; bct < 4; ++bct){
      f32x16v acc = zero16();
      #pragma unroll
      for (int ks = 0; ks < 3; ++ks){
        int row = bct * 32 + lo;
        int byte = row * 128 + ((16 * hi + 32 * ks) ^ ((row & 7) << 4));
        bfr8 bf = *(const bfr8*)((const char*)pb_lds + byte);
        acc = mfma32(af[ks], bf, acc);
      }
      int brow = bct * 32 + lo;
      #pragma unroll
      for (int w = 0; w < 4; ++w){
        u16x4 pk;
        #pragma unroll
        for (int rs = 0; rs < 4; ++rs){
          int hcol = hcol0 + rs + 8 * w + 4 * hi;
          float x = acc[4 * w + rs] + b1[hcol];
          float gl = 0.5f * x * (1.0f + erff(x * 0.70710678118654752f));
          pk[rs] = f2bf(gl);
        }
        int byte = (brow * 512 + (hcol0 + 8 * w + 4 * hi) * 2) ^ ((brow & 7) << 4);
        *(u16x4*)((char*)h_lds + byte) = pk;
      }
    }
  }
  __syncthreads();

  // phase 2: q^T = W2^T @ h^T -> Qws bf16
  const unsigned short* w2t = (const unsigned short*)(ws + OFF_W2T);
  unsigned short* qws = (unsigned short*)(ws + OFF_Q);
  const int qcol0 = wv * 32;
  bfr8 af2[16];
  #pragma unroll
  for (int ks = 0; ks < 16; ++ks)
    af2[ks] = *(const bfr8*)(w2t + (size_t)(qcol0 + lo) * 256 + 8 * hi + 16 * ks);
  for (int bct = 0; bct < 4; ++bct){
    f32x16v acc = zero16();
    int brow = bct * 32 + lo;
    #pragma unroll
    for (int ks = 0; ks < 16; ++ks){
      int byte = brow * 512 + ((16 * hi + 32 * ks) ^ ((brow & 7) << 4));
      bfr8 bf = *(const bfr8*)((const char*)h_lds + byte);
      acc = mfma32(af2[ks], bf, acc);
    }
    #pragma unroll
    for (int w = 0; w < 4; ++w){
      u16x4 pk;
      #pragma unroll
      for (int rs = 0; rs < 4; ++rs){
        int qcol = qcol0 + rs + 8 * w + 4 * hi;
        pk[rs] = f2bf(acc[4 * w + rs] + b2[qcol]);
      }
      *(u16x4*)(qws + (size_t)(bb + brow) * 128 + qcol0 + 8 * w + 4 * hi) = pk;
    }
  }
}

// ---------------- attention: swapped QK^T + in-register softmax + reg PV ----
// 512 WGs x 256 thr; 128 rows/WG (32/wave); 64 chunks of 64 pages.
// Double-buffered K LDS (one barrier/chunk); P never touches LDS.
__global__ __launch_bounds__(256, 2) void attn_kernel(const char* __restrict__ ws,
    const float* __restrict__ temp_p, float* __restrict__ out){
  __shared__ __align__(16) unsigned short k_lds[2][64 * 128];   // 2 x 16 KB, pre-swizzled

  const int tid = threadIdx.x;
  const int lane = tid & 63, wv = tid >> 6;
  const int lo = lane & 31, hi = lane >> 5;
  const int bb = blockIdx.x * 128;

  const unsigned short* qws = (const unsigned short*)(ws + OFF_Q);
  const unsigned short* kws = (const unsigned short*)(ws + OFF_K);
  const unsigned short* vt  = (const unsigned short*)(ws + OFF_V);

  const float scl = 1.0f / fmaxf(fabsf(temp_p[0]), 0.1f);
  const int qrow = bb + wv * 32 + lo;

  bfr8 qf[8];                                        // Q row in registers (B-frag: col=lo)
  #pragma unroll
  for (int ks = 0; ks < 8; ++ks)
    qf[ks] = *(const bfr8*)(qws + (size_t)qrow * 128 + 16 * ks + 8 * hi);

  f32x16v acc0 = zero16(), acc1 = zero16();          // C: col=lo -> vcol, row=crow -> query

  // prologue: stage chunk 0 into buf 0
  {
    const u16x8* src = (const u16x8*)(kws);
    u16x8* dst = (u16x8*)k_lds[0];
    #pragma unroll
    for (int i = 0; i < 4; ++i) dst[i * 256 + tid] = src[i * 256 + tid];
  }
  __syncthreads();

  for (int c = 0; c < 64; ++c){
    // issue next-chunk global loads early (latency hides under QK/exp/PV)
    u16x8 st[4];
    {
      int nc = (c < 63) ? c + 1 : 63;
      const u16x8* src = (const u16x8*)(kws + (size_t)nc * 8192);
      #pragma unroll
      for (int i = 0; i < 4; ++i) st[i] = src[i * 256 + tid];
    }

    // S^T = K @ Q^T: two 32-page tiles; lane holds one query (col=lo)
    const char* kb = (const char*)k_lds[c & 1];
    f32x16v s0 = zero16(), s1 = zero16();
    #pragma unroll
    for (int ks = 0; ks < 8; ++ks){
      int cb = ((16 * ks + 8 * hi) * 2) ^ ((lo & 7) << 4);
      bfr8 k0 = *(const bfr8*)(kb + lo * 256 + cb);
      bfr8 k1 = *(const bfr8*)(kb + (32 + lo) * 256 + cb);
      s0 = mfma32(k0, qf[ks], s0);
      s1 = mfma32(k1, qf[ks], s1);
    }

    // V B-fragments straight from global (L2/L1-resident)
    bfr8 vf0[4], vf1[4];
    #pragma unroll
    for (int kt = 0; kt < 4; ++kt){
      vf0[kt] = *(const bfr8*)(vt + (size_t)lo * 4096 + c * 64 + kt * 16 + 8 * hi);
      vf1[kt] = *(const bfr8*)(vt + (size_t)(32 + (lo & 15)) * 4096 + c * 64 + kt * 16 + 8 * hi);
    }

    // in-register softmax numerator + pack to PV A-fragments
    bfr8 pa0, pa1, pa2, pa3;
    tile_pack(s0, scl, pa0, pa1);                    // keys 0-15, 16-31
    tile_pack(s1, scl, pa2, pa3);                    // keys 32-47, 48-63

    acc0 = mfma32(pa0, vf0[0], acc0);  acc1 = mfma32(pa0, vf1[0], acc1);
    acc0 = mfma32(pa1, vf0[1], acc0);  acc1 = mfma32(pa1, vf1[1], acc1);
    acc0 = mfma32(pa2, vf0[2], acc0);  acc1 = mfma32(pa2, vf1[2], acc1);
    acc0 = mfma32(pa3, vf0[3], acc0);  acc1 = mfma32(pa3, vf1[3], acc1);

    // write staged next chunk into the other buffer, then one barrier
    {
      u16x8* dst = (u16x8*)k_lds[(c + 1) & 1];
      #pragma unroll
      for (int i = 0; i < 4; ++i) dst[i * 256 + tid] = st[i];
    }
    __syncthreads();
  }

  // epilogue: denom = vcol 40 = acc1 lane lo==8; broadcast via shuffle
  #pragma unroll
  for (int r = 0; r < 16; ++r){
    float dn = __shfl(acc1[r], (lane & 32) + 8, 64);
    float dinv = 1.0f / dn;
    int q = bb + wv * 32 + ((r & 3) + 8 * (r >> 2) + 4 * hi);
    float v0 = acc0[r] * dinv;
    out[(size_t)q * 52 + 12 + lo] = sigmoidf_(v0);
    if (lo < 8){
      float v1 = acc1[r] * dinv;
      out[(size_t)q * 52 + 44 + lo] = sigmoidf_(v1);
    }
  }
}

extern "C" void kernel_launch(void* const* d_in, const int* in_sizes, int n_in,
                              void* d_out, int out_size, void* d_ws, size_t ws_size,
                              hipStream_t stream){
  const float* vab      = (const float*)d_in[0];
  const float* mappings = (const float*)d_in[1];
  const float* keys     = (const float*)d_in[2];
  const float* perms    = (const float*)d_in[3];
  const float* W1       = (const float*)d_in[4];
  const float* b1       = (const float*)d_in[5];
  const float* W2       = (const float*)d_in[6];
  const float* b2       = (const float*)d_in[7];
  const float* temp     = (const float*)d_in[8];
  float* out = (float*)d_out;
  char*  ws  = (char*)d_ws;
  if (ws_size < WS_NEEDED) return;   // loud failure instead of OOB corruption

  prep_kernel<<<1200, 256, 0, stream>>>(mappings, keys, perms, W1, W2, ws);
  mlp_kernel<<<512, 256, 0, stream>>>(vab, b1, b2, ws, out);
  attn_kernel<<<512, 256, 0, stream>>>(ws, temp, out);
}